// Round 10
// baseline (2181.766 us; speedup 1.0000x reference)
//
#include <hip/hip_runtime.h>

// ---------------------------------------------------------------------------
// RNN_69526930588180: 3-layer SimpleRNN (tanh), B=256, T=256, D=64, H=512.
//
// Round 10: ROW-PARTITIONED IN-LDS RECURRENCE. The recurrence is row-
// independent, so a WG that owns 16 rows x ALL 512 cols keeps h in its own
// LDS and the recurrent chain has NO global round trip (r6/r8/r9 showed any
// store->poll->load hop costs 3-5us; this removes it).
//  * Wh (512KB) split: 13/16 in VGPRs (104 short8 frags = 416 regs/lane,
//    4 waves x 128 cols, 1 wave/SIMD) + 3/16 in LDS (512x104-pad = 104KB).
//    LDS: WhL 104KB + h ping-pong 32KB = 139,264 B (< r9's proven 148KB).
//  * proj WGs (col-tiled, Wx in LDS) feed xp = h_{l-1}@Wx via global, written
//    COLUMN-MAJOR [t][rg][col][row16] so both sides are coalesced dwordx2.
//    proj runs a hop ahead -> rec's per-step poll hits first try.
//  * h rings (64-deep, row-major for r9-style frag loads) feed proj_{l+1};
//    back-pressure = consumer's xp progress counter (acyclic, deadlock-free).
//  * Roster: 16 rowgroups x (rec0,1,2 + proj1 x4 + proj2 x4 + proj0) = 192
//    WGs x 256thr, rg co-placed on one XCD (%8 swizzle, r6-verified). Sync
//    protocol verbatim r6/r8/r9: FIFO RMW polls + per-wave atomic publish;
//    fast(same-XCD)=sc0, slow=sc0 sc1. Counters padded to 64B lines.
// ---------------------------------------------------------------------------

typedef unsigned short u16;
typedef unsigned int   u32;

typedef __attribute__((ext_vector_type(8))) short short8;
typedef __attribute__((ext_vector_type(4))) float f32x4;
typedef __attribute__((ext_vector_type(4))) int   i32x4;
typedef __attribute__((ext_vector_type(2))) int   i32x2;

#define N_B 256
#define N_T 256
#define N_D 64
#define N_H 512
#define NRG 16
#define RING 64
#define HSK_TGT 12

__device__ __forceinline__ u16 f2bf(float f) {
  union { float f; u32 u; } v; v.f = f;
  u32 u = v.u;
  u += 0x7fffu + ((u >> 16) & 1u);   // RNE
  return (u16)(u >> 16);
}
__device__ __forceinline__ float bf2f(u16 h) {
  union { u32 u; float f; } v; v.u = ((u32)h) << 16;
  return v.f;
}
__device__ __forceinline__ short8 ld8(const u16* p) { return *(const short8*)p; }
__device__ __forceinline__ short8 cvt8(const float* p) {
  short8 r;
#pragma unroll
  for (int j = 0; j < 8; ++j) r[j] = (short)f2bf(p[j]);
  return r;
}
__device__ __forceinline__ short8 as_s8(i32x4 v) {
  union { i32x4 i; short8 s; } u; u.i = v; return u.s;
}
__device__ __forceinline__ float fast_tanh(float x) {
  float xc = fminf(fmaxf(x, -9.f), 9.f);
  float e  = __builtin_amdgcn_exp2f(xc * 2.8853900817779268f);
  return 1.f - 2.f * __builtin_amdgcn_rcpf(e + 1.f);
}
// FIFO-fair coherence-point read (r6/r8/r9-proven).
__device__ __forceinline__ u32 rmw_read(u32* p) {
  u32 v, z = 0;
  asm volatile("global_atomic_add %0, %1, %2, off sc0\n\ts_waitcnt vmcnt(0)"
               : "=v"(v) : "v"(p), "v"(z) : "memory");
  return v;
}

// 16 batched A-fragment loads (row-major h, row fixed, k = kt*32 + quad*8).
__device__ __forceinline__ void load_frags16_fast(const u16* p, i32x4 f[16]) {
  asm volatile(
      "global_load_dwordx4 %0, %16, off sc0\n\t"
      "global_load_dwordx4 %1, %16, off offset:64 sc0\n\t"
      "global_load_dwordx4 %2, %16, off offset:128 sc0\n\t"
      "global_load_dwordx4 %3, %16, off offset:192 sc0\n\t"
      "global_load_dwordx4 %4, %16, off offset:256 sc0\n\t"
      "global_load_dwordx4 %5, %16, off offset:320 sc0\n\t"
      "global_load_dwordx4 %6, %16, off offset:384 sc0\n\t"
      "global_load_dwordx4 %7, %16, off offset:448 sc0\n\t"
      "global_load_dwordx4 %8, %16, off offset:512 sc0\n\t"
      "global_load_dwordx4 %9, %16, off offset:576 sc0\n\t"
      "global_load_dwordx4 %10, %16, off offset:640 sc0\n\t"
      "global_load_dwordx4 %11, %16, off offset:704 sc0\n\t"
      "global_load_dwordx4 %12, %16, off offset:768 sc0\n\t"
      "global_load_dwordx4 %13, %16, off offset:832 sc0\n\t"
      "global_load_dwordx4 %14, %16, off offset:896 sc0\n\t"
      "global_load_dwordx4 %15, %16, off offset:960 sc0\n\t"
      "s_waitcnt vmcnt(0)"
      : "=&v"(f[0]), "=&v"(f[1]), "=&v"(f[2]), "=&v"(f[3]),
        "=&v"(f[4]), "=&v"(f[5]), "=&v"(f[6]), "=&v"(f[7]),
        "=&v"(f[8]), "=&v"(f[9]), "=&v"(f[10]), "=&v"(f[11]),
        "=&v"(f[12]), "=&v"(f[13]), "=&v"(f[14]), "=&v"(f[15])
      : "v"(p) : "memory");
}
__device__ __forceinline__ void load_frags16_slow(const u16* p, i32x4 f[16]) {
  asm volatile(
      "global_load_dwordx4 %0, %16, off sc0 sc1\n\t"
      "global_load_dwordx4 %1, %16, off offset:64 sc0 sc1\n\t"
      "global_load_dwordx4 %2, %16, off offset:128 sc0 sc1\n\t"
      "global_load_dwordx4 %3, %16, off offset:192 sc0 sc1\n\t"
      "global_load_dwordx4 %4, %16, off offset:256 sc0 sc1\n\t"
      "global_load_dwordx4 %5, %16, off offset:320 sc0 sc1\n\t"
      "global_load_dwordx4 %6, %16, off offset:384 sc0 sc1\n\t"
      "global_load_dwordx4 %7, %16, off offset:448 sc0 sc1\n\t"
      "global_load_dwordx4 %8, %16, off offset:512 sc0 sc1\n\t"
      "global_load_dwordx4 %9, %16, off offset:576 sc0 sc1\n\t"
      "global_load_dwordx4 %10, %16, off offset:640 sc0 sc1\n\t"
      "global_load_dwordx4 %11, %16, off offset:704 sc0 sc1\n\t"
      "global_load_dwordx4 %12, %16, off offset:768 sc0 sc1\n\t"
      "global_load_dwordx4 %13, %16, off offset:832 sc0 sc1\n\t"
      "global_load_dwordx4 %14, %16, off offset:896 sc0 sc1\n\t"
      "global_load_dwordx4 %15, %16, off offset:960 sc0 sc1\n\t"
      "s_waitcnt vmcnt(0)"
      : "=&v"(f[0]), "=&v"(f[1]), "=&v"(f[2]), "=&v"(f[3]),
        "=&v"(f[4]), "=&v"(f[5]), "=&v"(f[6]), "=&v"(f[7]),
        "=&v"(f[8]), "=&v"(f[9]), "=&v"(f[10]), "=&v"(f[11]),
        "=&v"(f[12]), "=&v"(f[13]), "=&v"(f[14]), "=&v"(f[15])
      : "v"(p) : "memory");
}

#define MFMA16(a, b, c) __builtin_amdgcn_mfma_f32_16x16x32_bf16((a), (b), (c), 0, 0, 0)

// cnt layout (64B-padded lines): xp[l*16+rg] @ (l*16+rg)*16; h[l*16+rg] @
// (48+l*16+rg)*16; hsk arrive @ (80+rg)*16; hsk mask @ (96+rg)*16. 1792 u32.
#define CNT_U32 1792

__global__ __launch_bounds__(256, 1)
void rnn_wave(const float* __restrict__ x,
              const float* __restrict__ Wx0, const float* __restrict__ Wh0, const float* __restrict__ b0,
              const float* __restrict__ Wx1, const float* __restrict__ Wh1, const float* __restrict__ b1,
              const float* __restrict__ Wx2, const float* __restrict__ Wh2, const float* __restrict__ b2,
              u16* __restrict__ xp0, u16* __restrict__ xp1, u16* __restrict__ xp2,
              u16* __restrict__ hr0, u16* __restrict__ hr1, u16* __restrict__ h2last,
              u32* __restrict__ cnt) {
  const int s    = blockIdx.x >> 3;
  const int rg   = (blockIdx.x & 7) + 8 * (s & 1);  // rowgroup; XCD = blk%8
  const int role = s >> 1;                          // 0-2 rec, 3-10 proj12, 11 proj0
  const int tid  = threadIdx.x;
  const int lane = tid & 63;
  const int w    = tid >> 6;
  const int quad = lane >> 4;
  const int l16  = lane & 15;

  __shared__ __align__(16) u16 lds[69632];   // 139,264 B

  // handshake arrive (all 12 WGs of this rg)
  u32 xcc;
  asm volatile("s_getreg_b32 %0, hwreg(HW_REG_XCC_ID)" : "=s"(xcc));
  if (tid == 0) {
    __hip_atomic_fetch_or(&cnt[(96 + rg) * 16], 1u << (xcc & 7), __ATOMIC_RELAXED,
                          __HIP_MEMORY_SCOPE_AGENT);
    asm volatile("s_waitcnt vmcnt(0)" ::: "memory");
    __hip_atomic_fetch_add(&cnt[(80 + rg) * 16], 1u, __ATOMIC_RELAXED,
                           __HIP_MEMORY_SCOPE_AGENT);
  }

  if (role < 3) {
    // ======================= REC: 16 rows x 512 cols =======================
    const int l = role;
    const float* Wh   = (l == 0) ? Wh0 : (l == 1) ? Wh1 : Wh2;
    const float* bias = (l == 0) ? b0  : (l == 1) ? b1  : b2;
    const u16* xp     = (l == 0) ? xp0 : (l == 1) ? xp1 : xp2;
    u16* hout         = (l == 0) ? hr0 : (l == 1) ? hr1 : nullptr;
    const u32 PJ = (l == 0) ? 4u : 16u;  // xp publishes per step
    u32* my_xp_cnt  = &cnt[(l * 16 + rg) * 16];
    u32* nxt_xp_cnt = (l < 2) ? &cnt[((l + 1) * 16 + rg) * 16] : nullptr;
    u32* my_h_cnt   = (l < 2) ? &cnt[(48 + l * 16 + rg) * 16] : nullptr;

    // Wh frags kt 0..12 -> regs (each lane: 8 col-strided fp32 gathers, coalesced across lanes)
    short8 whr[104];
#pragma unroll
    for (int kt = 0; kt < 13; ++kt) {
#pragma unroll
      for (int nt = 0; nt < 8; ++nt) {
        const float* wp = Wh + (size_t)(kt * 32 + quad * 8) * N_H + (w * 128 + nt * 16 + l16);
        short8 f;
#pragma unroll
        for (int jj = 0; jj < 8; ++jj) f[jj] = (short)f2bf(wp[(size_t)jj * N_H]);
        whr[kt * 8 + nt] = f;
      }
    }
    // Wh kt 13..15 -> LDS WhL[n][krel], padded row = 104 u16 (208B = 13x16 ok)
    for (int e = tid; e < 512 * 96; e += 256) {
      int n = e & 511, krel = e >> 9;
      lds[n * 104 + krel] = f2bf(Wh[(size_t)(416 + krel) * N_H + n]);
    }
    float bv[8];
#pragma unroll
    for (int nt = 0; nt < 8; ++nt) bv[nt] = bias[w * 128 + nt * 16 + l16];

    // fast-path decision (per-wave lane0 + readfirstlane)
    u32 fv = 0;
    if (lane == 0) {
      u32 it = 0;
      while (rmw_read(&cnt[(80 + rg) * 16]) < (u32)HSK_TGT) {
        __builtin_amdgcn_s_sleep(1);
        if (++it > (1u << 22)) break;
      }
      if (it <= (1u << 22)) {
        u32 m = rmw_read(&cnt[(96 + rg) * 16]);
        fv = (m != 0u && (m & (m - 1u)) == 0u) ? 1u : 0u;
      }
    }
    const bool fast = __builtin_amdgcn_readfirstlane(fv) != 0;
    __syncthreads();

    const int HB = 53248;  // u16 index of h ping-pong
    bool dead = false;

#pragma clang loop unroll(disable)
    for (int t = 0; t < N_T; ++t) {
      const int par = t & 1;
      // poll xp(t) ready; ring back-pressure vs next layer's consumption
      if (lane == 0 && !dead) {
        u32 it = 0;
        for (;;) {
          u32 v = fast ? rmw_read(my_xp_cnt)
                       : __hip_atomic_load(my_xp_cnt, __ATOMIC_RELAXED, __HIP_MEMORY_SCOPE_AGENT);
          if (v >= PJ * (u32)(t + 1)) break;
          __builtin_amdgcn_s_sleep(1);
          if (++it > (1u << 22)) { dead = true; break; }
        }
        if (l < 2 && t >= RING && !dead) {
          it = 0;
          for (;;) {
            u32 v = fast ? rmw_read(nxt_xp_cnt)
                         : __hip_atomic_load(nxt_xp_cnt, __ATOMIC_RELAXED, __HIP_MEMORY_SCOPE_AGENT);
            if (v >= 16u * (u32)(t - RING + 1)) break;
            __builtin_amdgcn_s_sleep(1);
            if (++it > (1u << 22)) { dead = true; break; }
          }
        }
      }
      // issue xp loads (8 x dwordx2, col-major layout), consume after MFMA
      i32x2 xq0, xq1, xq2, xq3, xq4, xq5, xq6, xq7;
      {
        const u16* xb = xp + ((size_t)(t * 16 + rg) * 512 + w * 128 + l16) * 16 + quad * 4;
        if (fast) {
          asm volatile(
              "global_load_dwordx2 %0, %8, off sc0\n\t"
              "global_load_dwordx2 %1, %8, off offset:512 sc0\n\t"
              "global_load_dwordx2 %2, %8, off offset:1024 sc0\n\t"
              "global_load_dwordx2 %3, %8, off offset:1536 sc0\n\t"
              "global_load_dwordx2 %4, %8, off offset:2048 sc0\n\t"
              "global_load_dwordx2 %5, %8, off offset:2560 sc0\n\t"
              "global_load_dwordx2 %6, %8, off offset:3072 sc0\n\t"
              "global_load_dwordx2 %7, %8, off offset:3584 sc0"
              : "=&v"(xq0), "=&v"(xq1), "=&v"(xq2), "=&v"(xq3),
                "=&v"(xq4), "=&v"(xq5), "=&v"(xq6), "=&v"(xq7)
              : "v"(xb) : "memory");
        } else {
          asm volatile(
              "global_load_dwordx2 %0, %8, off sc0 sc1\n\t"
              "global_load_dwordx2 %1, %8, off offset:512 sc0 sc1\n\t"
              "global_load_dwordx2 %2, %8, off offset:1024 sc0 sc1\n\t"
              "global_load_dwordx2 %3, %8, off offset:1536 sc0 sc1\n\t"
              "global_load_dwordx2 %4, %8, off offset:2048 sc0 sc1\n\t"
              "global_load_dwordx2 %5, %8, off offset:2560 sc0 sc1\n\t"
              "global_load_dwordx2 %6, %8, off offset:3072 sc0 sc1\n\t"
              "global_load_dwordx2 %7, %8, off offset:3584 sc0 sc1"
              : "=&v"(xq0), "=&v"(xq1), "=&v"(xq2), "=&v"(xq3),
                "=&v"(xq4), "=&v"(xq5), "=&v"(xq6), "=&v"(xq7)
              : "v"(xb) : "memory");
        }
      }
      // recurrent h(t-1)@Wh from LDS A + reg/LDS B
      f32x4 acc[8] = {{0.f,0.f,0.f,0.f},{0.f,0.f,0.f,0.f},{0.f,0.f,0.f,0.f},{0.f,0.f,0.f,0.f},
                      {0.f,0.f,0.f,0.f},{0.f,0.f,0.f,0.f},{0.f,0.f,0.f,0.f},{0.f,0.f,0.f,0.f}};
      if (t > 0) {
        const int hbR = HB + (par ? 8192 : 0);
#pragma unroll
        for (int kt = 0; kt < 13; ++kt) {
          short8 a = ld8(&lds[hbR + l16 * 512 + ((kt * 32 + quad * 8 + 8 * l16) & 511)]);
#pragma unroll
          for (int nt = 0; nt < 8; ++nt)
            acc[nt] = MFMA16(a, whr[kt * 8 + nt], acc[nt]);
        }
#pragma unroll
        for (int ktl = 0; ktl < 3; ++ktl) {
          short8 a = ld8(&lds[hbR + l16 * 512 + (((13 + ktl) * 32 + quad * 8 + 8 * l16) & 511)]);
#pragma unroll
          for (int nt = 0; nt < 8; ++nt) {
            short8 b = ld8(&lds[(w * 128 + nt * 16 + l16) * 104 + ktl * 32 + quad * 8]);
            acc[nt] = MFMA16(a, b, acc[nt]);
          }
        }
      }
      asm volatile("s_waitcnt vmcnt(0)" ::: "memory");  // xp arrived
      // combine + tanh; pack bf16 pairs (rows quad*4+{0,1} and {2,3})
      u32 hpk[16];
      {
        i32x2 xq[8] = {xq0, xq1, xq2, xq3, xq4, xq5, xq6, xq7};
#pragma unroll
        for (int nt = 0; nt < 8; ++nt) {
          u32 wa = (u32)xq[nt].x, wb = (u32)xq[nt].y;
          float u0 = acc[nt][0] + bf2f((u16)(wa & 0xffffu)) + bv[nt];
          float u1 = acc[nt][1] + bf2f((u16)(wa >> 16))     + bv[nt];
          float u2 = acc[nt][2] + bf2f((u16)(wb & 0xffffu)) + bv[nt];
          float u3 = acc[nt][3] + bf2f((u16)(wb >> 16))     + bv[nt];
          hpk[nt * 2]     = (u32)f2bf(fast_tanh(u0)) | ((u32)f2bf(fast_tanh(u1)) << 16);
          hpk[nt * 2 + 1] = (u32)f2bf(fast_tanh(u2)) | ((u32)f2bf(fast_tanh(u3)) << 16);
        }
      }
      // write h(t) to LDS ping-pong (rotated row-major)
      {
        const int hbW = HB + (par ? 0 : 8192);
#pragma unroll
        for (int nt = 0; nt < 8; ++nt) {
          int col = w * 128 + nt * 16 + l16;
#pragma unroll
          for (int r = 0; r < 4; ++r) {
            int row = quad * 4 + r;
            u16 hv = (u16)((hpk[nt * 2 + (r >> 1)] >> ((r & 1) * 16)) & 0xffffu);
            lds[hbW + row * 512 + ((col + 8 * row) & 511)] = hv;
          }
        }
      }
      // publish h(t) to ring (row-major) for proj_{l+1}; l==2 -> only final h
      if (l < 2) {
        u16* rb = hout + ((size_t)(rg * RING + (t & (RING - 1))) * 16 + quad * 4) * 512;
#pragma unroll
        for (int nt = 0; nt < 8; ++nt) {
          u16* p = rb + w * 128 + nt * 16 + l16;
          u32 v0 = hpk[nt * 2] & 0xffffu,     v1 = hpk[nt * 2] >> 16;
          u32 v2 = hpk[nt * 2 + 1] & 0xffffu, v3 = hpk[nt * 2 + 1] >> 16;
          if (fast) {
            asm volatile(
                "global_store_short %0, %1, off sc0\n\t"
                "global_store_short %0, %2, off offset:1024 sc0\n\t"
                "global_store_short %0, %3, off offset:2048 sc0\n\t"
                "global_store_short %0, %4, off offset:3072 sc0"
                :: "v"(p), "v"(v0), "v"(v1), "v"(v2), "v"(v3) : "memory");
          } else {
            asm volatile(
                "global_store_short %0, %1, off sc0 sc1\n\t"
                "global_store_short %0, %2, off offset:1024 sc0 sc1\n\t"
                "global_store_short %0, %3, off offset:2048 sc0 sc1\n\t"
                "global_store_short %0, %4, off offset:3072 sc0 sc1"
                :: "v"(p), "v"(v0), "v"(v1), "v"(v2), "v"(v3) : "memory");
          }
        }
      } else if (t == N_T - 1) {
#pragma unroll
        for (int nt = 0; nt < 8; ++nt) {
          int col = w * 128 + nt * 16 + l16;
#pragma unroll
          for (int r = 0; r < 4; ++r)
            h2last[(size_t)(rg * 16 + quad * 4 + r) * 512 + col] =
                (u16)((hpk[nt * 2 + (r >> 1)] >> ((r & 1) * 16)) & 0xffffu);
        }
      }
      asm volatile("s_waitcnt vmcnt(0)" ::: "memory");
      if (l < 2 && lane == 0) {
        if (fast) {
          u32 one = 1u;
          asm volatile("global_atomic_add %0, %1, off" :: "v"(my_h_cnt), "v"(one) : "memory");
        } else {
          __hip_atomic_fetch_add(my_h_cnt, 1u, __ATOMIC_RELAXED, __HIP_MEMORY_SCOPE_AGENT);
        }
      }
      __syncthreads();  // h(t) visible in LDS to all waves for t+1
    }
  } else if (role < 11) {
    // ================= PROJ l=1,2: 16 rows x 128 cols (ct) =================
    const int l  = (role < 7) ? 1 : 2;
    const int ct = (role - 3) & 3;
    const float* Wx = (l == 1) ? Wx1 : Wx2;
    const u16* hin  = (l == 1) ? hr0 : hr1;
    u16* xpo        = (l == 1) ? xp1 : xp2;
    u32* src_cnt = &cnt[(48 + (l - 1) * 16 + rg) * 16];
    u32* dst_cnt = &cnt[(l * 16 + rg) * 16];

    for (int e = tid; e < 128 * 512; e += 256) {
      int n = e & 127, k = e >> 7;
      lds[n * 512 + ((k + 8 * n) & 511)] = f2bf(Wx[(size_t)k * N_H + ct * 128 + n]);
    }
    u32 fv = 0;
    if (lane == 0) {
      u32 it = 0;
      while (rmw_read(&cnt[(80 + rg) * 16]) < (u32)HSK_TGT) {
        __builtin_amdgcn_s_sleep(1);
        if (++it > (1u << 22)) break;
      }
      if (it <= (1u << 22)) {
        u32 m = rmw_read(&cnt[(96 + rg) * 16]);
        fv = (m != 0u && (m & (m - 1u)) == 0u) ? 1u : 0u;
      }
    }
    const bool fast = __builtin_amdgcn_readfirstlane(fv) != 0;
    __syncthreads();

    const int n0 = w * 32 + l16, n1 = w * 32 + 16 + l16;
    bool dead = false;
#pragma clang loop unroll(disable)
    for (int t = 0; t < N_T; ++t) {
      if (lane == 0 && !dead) {
        u32 it = 0;
        for (;;) {
          u32 v = fast ? rmw_read(src_cnt)
                       : __hip_atomic_load(src_cnt, __ATOMIC_RELAXED, __HIP_MEMORY_SCOPE_AGENT);
          if (v >= 4u * (u32)(t + 1)) break;
          __builtin_amdgcn_s_sleep(1);
          if (++it > (1u << 22)) { dead = true; break; }
        }
      }
      const u16* ap = hin + (((size_t)(rg * RING + (t & (RING - 1))) * 16 + l16) * 512 + quad * 8);
      i32x4 fr[16];
      if (fast) load_frags16_fast(ap, fr);
      else      load_frags16_slow(ap, fr);
      f32x4 a0 = {0.f, 0.f, 0.f, 0.f}, a1 = {0.f, 0.f, 0.f, 0.f};
#pragma unroll
      for (int kt = 0; kt < 16; ++kt) {
        short8 a = as_s8(fr[kt]);
        a0 = MFMA16(a, ld8(&lds[n0 * 512 + ((kt * 32 + quad * 8 + 8 * n0) & 511)]), a0);
        a1 = MFMA16(a, ld8(&lds[n1 * 512 + ((kt * 32 + quad * 8 + 8 * n1) & 511)]), a1);
      }
      // store xp col-major: per nt one dwordx2 = rows quad*4..+3
      {
        u16* xb = xpo + ((size_t)(t * 16 + rg) * 512 + ct * 128 + w * 32 + l16) * 16 + quad * 4;
        i32x2 d0, d1;
        d0.x = (int)((u32)f2bf(a0[0]) | ((u32)f2bf(a0[1]) << 16));
        d0.y = (int)((u32)f2bf(a0[2]) | ((u32)f2bf(a0[3]) << 16));
        d1.x = (int)((u32)f2bf(a1[0]) | ((u32)f2bf(a1[1]) << 16));
        d1.y = (int)((u32)f2bf(a1[2]) | ((u32)f2bf(a1[3]) << 16));
        if (fast) {
          asm volatile(
              "global_store_dwordx2 %0, %1, off sc0\n\t"
              "global_store_dwordx2 %0, %2, off offset:512 sc0"
              :: "v"(xb), "v"(d0), "v"(d1) : "memory");
        } else {
          asm volatile(
              "global_store_dwordx2 %0, %1, off sc0 sc1\n\t"
              "global_store_dwordx2 %0, %2, off offset:512 sc0 sc1"
              :: "v"(xb), "v"(d0), "v"(d1) : "memory");
        }
      }
      asm volatile("s_waitcnt vmcnt(0)" ::: "memory");
      if (lane == 0) {
        if (fast) {
          u32 one = 1u;
          asm volatile("global_atomic_add %0, %1, off" :: "v"(dst_cnt), "v"(one) : "memory");
        } else {
          __hip_atomic_fetch_add(dst_cnt, 1u, __ATOMIC_RELAXED, __HIP_MEMORY_SCOPE_AGENT);
        }
      }
    }
  } else {
    // ==================== PROJ0: x@Wx0, 16 rows x 512 cols ==================
    u32* dst_cnt = &cnt[(0 * 16 + rg) * 16];
    short8 wxr[16];
#pragma unroll
    for (int kt = 0; kt < 2; ++kt) {
#pragma unroll
      for (int nt = 0; nt < 8; ++nt) {
        const float* wp = Wx0 + (size_t)(kt * 32 + quad * 8) * N_H + (w * 128 + nt * 16 + l16);
        short8 f;
#pragma unroll
        for (int jj = 0; jj < 8; ++jj) f[jj] = (short)f2bf(wp[(size_t)jj * N_H]);
        wxr[kt * 8 + nt] = f;
      }
    }
    u32 fv = 0;
    if (lane == 0) {
      u32 it = 0;
      while (rmw_read(&cnt[(80 + rg) * 16]) < (u32)HSK_TGT) {
        __builtin_amdgcn_s_sleep(1);
        if (++it > (1u << 22)) break;
      }
      if (it <= (1u << 22)) {
        u32 m = rmw_read(&cnt[(96 + rg) * 16]);
        fv = (m != 0u && (m & (m - 1u)) == 0u) ? 1u : 0u;
      }
    }
    const bool fast = __builtin_amdgcn_readfirstlane(fv) != 0;
    __syncthreads();

#pragma clang loop unroll(disable)
    for (int t = 0; t < N_T; ++t) {
      const float* xa = x + ((size_t)(rg * 16 + l16) * N_T + t) * N_D + quad * 8;
      short8 a0 = cvt8(xa), a1 = cvt8(xa + 32);
      f32x4 acc[8] = {{0.f,0.f,0.f,0.f},{0.f,0.f,0.f,0.f},{0.f,0.f,0.f,0.f},{0.f,0.f,0.f,0.f},
                      {0.f,0.f,0.f,0.f},{0.f,0.f,0.f,0.f},{0.f,0.f,0.f,0.f},{0.f,0.f,0.f,0.f}};
#pragma unroll
      for (int nt = 0; nt < 8; ++nt) {
        acc[nt] = MFMA16(a0, wxr[nt], acc[nt]);
        acc[nt] = MFMA16(a1, wxr[8 + nt], acc[nt]);
      }
      u16* xb = xp0 + ((size_t)(t * 16 + rg) * 512 + w * 128 + l16) * 16 + quad * 4;
#pragma unroll
      for (int nt = 0; nt < 8; ++nt) {
        i32x2 d;
        d.x = (int)((u32)f2bf(acc[nt][0]) | ((u32)f2bf(acc[nt][1]) << 16));
        d.y = (int)((u32)f2bf(acc[nt][2]) | ((u32)f2bf(acc[nt][3]) << 16));
        u16* p = xb + nt * 256;
        if (fast) {
          asm volatile("global_store_dwordx2 %0, %1, off sc0" :: "v"(p), "v"(d) : "memory");
        } else {
          asm volatile("global_store_dwordx2 %0, %1, off sc0 sc1" :: "v"(p), "v"(d) : "memory");
        }
      }
      asm volatile("s_waitcnt vmcnt(0)" ::: "memory");
      if (lane == 0) {
        if (fast) {
          u32 one = 1u;
          asm volatile("global_atomic_add %0, %1, off" :: "v"(dst_cnt), "v"(one) : "memory");
        } else {
          __hip_atomic_fetch_add(dst_cnt, 1u, __ATOMIC_RELAXED, __HIP_MEMORY_SCOPE_AGENT);
        }
      }
    }
  }
}

// out[b] = h2last[b][:] . Wf + bf
__global__ void head_kernel(const u16* __restrict__ h2last, const float* __restrict__ Wf,
                            const float* __restrict__ bf, float* __restrict__ out) {
  int b    = blockIdx.x;
  int lane = threadIdx.x;  // 64
  const u16* hrow = h2last + (size_t)b * N_H;
  float s = 0.f;
#pragma unroll
  for (int r = 0; r < N_H / 64; ++r) {
    int idx = lane * 8 + r;
    s += bf2f(hrow[idx]) * Wf[idx];
  }
#pragma unroll
  for (int off = 32; off > 0; off >>= 1) s += __shfl_down(s, off);
  if (lane == 0) out[b] = s + bf[0];
}

extern "C" void kernel_launch(void* const* d_in, const int* in_sizes, int n_in,
                              void* d_out, int out_size, void* d_ws, size_t ws_size,
                              hipStream_t stream) {
  const float* x   = (const float*)d_in[0];
  const float* Wx0 = (const float*)d_in[1];
  const float* Wh0 = (const float*)d_in[2];
  const float* b0  = (const float*)d_in[3];
  const float* Wx1 = (const float*)d_in[4];
  const float* Wh1 = (const float*)d_in[5];
  const float* b1  = (const float*)d_in[6];
  const float* Wx2 = (const float*)d_in[7];
  const float* Wh2 = (const float*)d_in[8];
  const float* b2  = (const float*)d_in[9];
  const float* Wf  = (const float*)d_in[10];
  const float* bf  = (const float*)d_in[11];
  float* out = (float*)d_out;

  const size_t XP_BYTES = (size_t)N_T * NRG * 512 * 16 * sizeof(u16);   // 67,108,864
  const size_t HR_BYTES = (size_t)NRG * RING * 16 * 512 * sizeof(u16);  // 16,777,216
  const size_t H2_BYTES = (size_t)N_B * N_H * sizeof(u16);              // 262,144
  const size_t TOTAL = 3 * XP_BYTES + 2 * HR_BYTES + H2_BYTES + CNT_U32 * sizeof(u32);
  if (ws_size < TOTAL) return;  // loud fail

  char* ws  = (char*)d_ws;
  u16* xp0  = (u16*)(ws);
  u16* xp1  = (u16*)(ws + XP_BYTES);
  u16* xp2  = (u16*)(ws + 2 * XP_BYTES);
  u16* hr0  = (u16*)(ws + 3 * XP_BYTES);
  u16* hr1  = (u16*)(ws + 3 * XP_BYTES + HR_BYTES);
  u16* h2l  = (u16*)(ws + 3 * XP_BYTES + 2 * HR_BYTES);
  u32* cnt  = (u32*)(ws + 3 * XP_BYTES + 2 * HR_BYTES + H2_BYTES);

  (void)hipMemsetAsync(cnt, 0, CNT_U32 * sizeof(u32), stream);

  rnn_wave<<<192, 256, 0, stream>>>(x, Wx0, Wh0, b0, Wx1, Wh1, b1, Wx2, Wh2, b2,
                                    xp0, xp1, xp2, hr0, hr1, h2l, cnt);
  head_kernel<<<N_B, 64, 0, stream>>>(h2l, Wf, bf, out);
}